// Round 6
// baseline (398.591 us; speedup 1.0000x reference)
//
#include <hip/hip_runtime.h>
#include <hip/hip_bf16.h>
#include <cmath>

// FeedForwardQuantum: out = relu(cumprod(cos(x[...,:8])) @ w1^T + b1) @ w2^T + b2
// B=4 T=4096 C=1024 F=4096 -> M=16384 tokens, GEMM [M,4096]x[4096,1024]^T.
// Round-5: H is never materialized in HBM — A-tiles are computed in-kernel
// (q from LDS, per-kt w1^T slice staged to LDS) and ds_write-staged into the
// same swizzled LDS layout the MFMA side already consumes.

typedef __attribute__((ext_vector_type(8))) __bf16 bf16x8;
typedef __attribute__((ext_vector_type(4))) float f32x4;
typedef __attribute__((ext_vector_type(8))) unsigned short ushortx8;

#define GAS __attribute__((address_space(1)))
#define LAS __attribute__((address_space(3)))

__device__ __forceinline__ unsigned short f32_to_bf16(float f) {
    union { float f; unsigned int u; } v; v.f = f;
    unsigned int u = v.u;
    u += 0x7FFFu + ((u >> 16) & 1u);   // round-to-nearest-even
    return (unsigned short)(u >> 16);
}

// ---------------- kernel 1: w2 fp32 -> bf16 ----------------
__global__ __launch_bounds__(256) void cvt_w2(const float* __restrict__ src,
                                              unsigned short* __restrict__ dst) {
    int i = blockIdx.x * 256 + threadIdx.x;       // 8 elements per thread
    const float4* s = reinterpret_cast<const float4*>(src);
    float4 a = s[2 * i], b = s[2 * i + 1];
    ushortx8 o;
    o[0] = f32_to_bf16(a.x); o[1] = f32_to_bf16(a.y);
    o[2] = f32_to_bf16(a.z); o[3] = f32_to_bf16(a.w);
    o[4] = f32_to_bf16(b.x); o[5] = f32_to_bf16(b.y);
    o[6] = f32_to_bf16(b.z); o[7] = f32_to_bf16(b.w);
    reinterpret_cast<ushortx8*>(dst)[i] = o;
}

// ---------------- kernel 2: fused 256x256 8-phase GEMM -----------------------
// C[M,N] = relu(q @ w1^T + b1) @ B^T + bias.  B[N,K]=w2 bf16.  BM=BN=256,
// BK=64, 512 thr (8 waves 2Mx4N), LDS: A/B [2][2][2][128x64] bf16 (128K) +
// qs[256][8] f32 (8K) + w1s[2][576] f32 (4.5K).  A staged by COMPUTE (VALU,
// interleaved with MFMA cluster); B and w1-slice staged by global_load_lds.
// vmcnt ledger per kt (issues: ph0 B0x2; ph1 B1x2 + Wx2):
//   end ph0: vmcnt(4)  [drain B1(kt) for ph1]
//   end ph1: vmcnt(6)  [drain W(kt+1) for ph2's COMPUTE]
//   end ph2: none
//   end ph3: vmcnt(4)  [drain B0(kt+1) for next ph0]
// All stages unconditional with K-tile index wrapped &63 (uniform ledger, no
// tail races; wrapped stages land in buffers never consumed).
__global__ __launch_bounds__(512, 2) void gemm_fused(const float* __restrict__ x,
                                                     const float* __restrict__ w1,
                                                     const float* __restrict__ b1,
                                                     const unsigned short* __restrict__ B,
                                                     const float* __restrict__ bias,
                                                     float* __restrict__ C) {
    constexpr int M = 16384, N = 1024, K = 4096;
    constexpr int BM = 256, BN = 256, BK = 64;
    constexpr int NKT = K / BK;                 // 64 K-tiles

    __shared__ __align__(16) unsigned short lds[2][2][2][128 * 64];  // 128 KiB
    __shared__ float qs[256][8];                 // 8 KiB: cumprod(cos(x)) rows
    __shared__ float w1s[2][576];                // 2x(512 w1T + 64 b1) f32

    const int tid  = threadIdx.x;
    const int wv   = tid >> 6;
    const int lane = tid & 63;
    const int wr   = wv >> 2;                   // 2 waves in M
    const int wc   = wv & 3;                    // 4 waves in N
    const int rl   = lane & 15;
    const int kq4  = lane >> 4;

    // XCD-local swizzle: XCD x owns tm in [x*8, x*8+8) x all 4 tn.
    const int bid = blockIdx.x;
    const int xcd = bid & 7;
    const int loc = bid >> 3;                   // 0..31
    const int tm  = xcd * 8 + (loc & 7);        // 0..63
    const int tn  = loc >> 3;                   // 0..3
    const int rowBase = tm * BM;
    const int colBase = tn * BN;

    // ---- staging geometry ----
    const int i0  = tid >> 3;                            // row in half-tile
    const int sw8 = ((tid & 7) ^ (i0 & 7)) * 8;          // swizzled col chunk (elems)
    const int bR0 = (i0 & 31) + ((i0 >> 5) << 6);
    const unsigned short* pB0 = B + (size_t)(colBase + bR0) * K + sw8;
    const unsigned short* pB1 = B + (size_t)(colBase + bR0 + 128) * K + sw8;

#define STAGE_B(HH, BB, KT)  do {                                                   \
    __builtin_amdgcn_global_load_lds((const GAS unsigned int*)(const void*)          \
        (pB0 + (size_t)(HH) * 32 * K + (KT) * 64),                                   \
        (LAS unsigned int*)(void*)&lds[BB][1][HH][tid * 8], 16, 0, 0);               \
    __builtin_amdgcn_global_load_lds((const GAS unsigned int*)(const void*)          \
        (pB1 + (size_t)(HH) * 32 * K + (KT) * 64),                                   \
        (LAS unsigned int*)(void*)&lds[BB][1][HH][4096 + tid * 8], 16, 0, 0);        \
} while (0)

// w1T slice: w1s[slot][j*64 + f_local] = w1[kt*64 + f_local][j]; b1 at [512+..].
// b1 part issued identically by all 8 waves (same dest, same data — benign).
#define STAGE_W(SLOT, KT)  do {                                                     \
    __builtin_amdgcn_global_load_lds((const GAS unsigned int*)(const void*)          \
        (w1 + (size_t)((KT) * 64 + (tid & 63)) * 8 + (tid >> 6)),                    \
        (LAS unsigned int*)(void*)&w1s[SLOT][tid], 4, 0, 0);                         \
    __builtin_amdgcn_global_load_lds((const GAS unsigned int*)(const void*)          \
        (b1 + (KT) * 64 + lane),                                                     \
        (LAS unsigned int*)(void*)&w1s[SLOT][512 + lane], 4, 0, 0);                  \
} while (0)

// Compute 16 H values (rows r0, r0+128 local; f = kt*64 + sw8..sw8+8) and
// ds_write into the swizzled A-slot this thread used to gload_lds-stage.
#define COMPUTE_A(HH, BB, SLOT) do {                                                 \
    const int r0_ = (HH) * 64 + i0;                                                  \
    f32x4 q0a = *(const f32x4*)&qs[r0_][0],       q0b = *(const f32x4*)&qs[r0_][4];  \
    f32x4 q1a = *(const f32x4*)&qs[r0_ + 128][0], q1b = *(const f32x4*)&qs[r0_ + 128][4]; \
    f32x4 bba = *(const f32x4*)&w1s[SLOT][512 + sw8];                                \
    f32x4 bbb = *(const f32x4*)&w1s[SLOT][512 + sw8 + 4];                            \
    float a0_[8], a1_[8];                                                            \
    _Pragma("unroll") for (int u = 0; u < 4; ++u) {                                  \
        a0_[u] = bba[u]; a0_[4 + u] = bbb[u];                                        \
        a1_[u] = bba[u]; a1_[4 + u] = bbb[u]; }                                      \
    _Pragma("unroll") for (int j = 0; j < 8; ++j) {                                  \
        f32x4 wA = *(const f32x4*)&w1s[SLOT][j * 64 + sw8];                          \
        f32x4 wB = *(const f32x4*)&w1s[SLOT][j * 64 + sw8 + 4];                      \
        float qj0 = (j < 4) ? q0a[j & 3] : q0b[j & 3];                               \
        float qj1 = (j < 4) ? q1a[j & 3] : q1b[j & 3];                               \
        _Pragma("unroll") for (int u = 0; u < 4; ++u) {                              \
            a0_[u] += qj0 * wA[u]; a0_[4 + u] += qj0 * wB[u];                        \
            a1_[u] += qj1 * wA[u]; a1_[4 + u] += qj1 * wB[u]; } }                    \
    bf16x8 h0_, h1_;                                                                 \
    _Pragma("unroll") for (int u = 0; u < 8; ++u) {                                  \
        h0_[u] = (__bf16)fmaxf(a0_[u], 0.0f);                                        \
        h1_[u] = (__bf16)fmaxf(a1_[u], 0.0f); }                                      \
    *reinterpret_cast<bf16x8*>(&lds[BB][0][HH][tid * 8]) = h0_;                      \
    *reinterpret_cast<bf16x8*>(&lds[BB][0][HH][4096 + tid * 8]) = h1_;               \
} while (0)

    // ---- ds_read offsets (elements) ----
    const int ch0  = ((0 + kq4) ^ (rl & 7)) * 8;        // k-half 0 chunk
    const int ch1  = ((4 + kq4) ^ (rl & 7)) * 8;        // k-half 1 chunk
    const int aOff = (wr * 64 + rl) * 64;
    const int bOff = (wc * 32 + rl) * 64;

    bf16x8 aF[4][2], bF0[2][2], bF1[2][2];
    f32x4 acc[8][4];
    #pragma unroll
    for (int m = 0; m < 8; ++m)
        #pragma unroll
        for (int n = 0; n < 4; ++n) acc[m][n] = (f32x4){0.f, 0.f, 0.f, 0.f};

#define LOAD_A(HH) { _Pragma("unroll")                                               \
    for (int m_ = 0; m_ < 4; ++m_) {                                                 \
        aF[m_][0] = *(const bf16x8*)&lds[b][0][HH][aOff + m_ * 1024 + ch0];          \
        aF[m_][1] = *(const bf16x8*)&lds[b][0][HH][aOff + m_ * 1024 + ch1]; } }
#define LOAD_B(DST, HH) { _Pragma("unroll")                                          \
    for (int n_ = 0; n_ < 2; ++n_) {                                                 \
        DST[n_][0] = *(const bf16x8*)&lds[b][1][HH][bOff + n_ * 1024 + ch0];         \
        DST[n_][1] = *(const bf16x8*)&lds[b][1][HH][bOff + n_ * 1024 + ch1]; } }
#define MFMA_QUAD(BF, MO, NO) { _Pragma("unroll")                                    \
    for (int m_ = 0; m_ < 4; ++m_) { _Pragma("unroll")                               \
        for (int n_ = 0; n_ < 2; ++n_) {                                             \
            acc[MO + m_][NO + n_] = __builtin_amdgcn_mfma_f32_16x16x32_bf16(         \
                aF[m_][0], BF[n_][0], acc[MO + m_][NO + n_], 0, 0, 0);               \
            acc[MO + m_][NO + n_] = __builtin_amdgcn_mfma_f32_16x16x32_bf16(         \
                aF[m_][1], BF[n_][1], acc[MO + m_][NO + n_], 0, 0, 0); } } }
#define VM4 asm volatile("s_waitcnt vmcnt(4)" ::: "memory");
#define VM6 asm volatile("s_waitcnt vmcnt(6)" ::: "memory");
#define PHASE_TAIL(MFMAS, VMW) do {                                                  \
    __builtin_amdgcn_s_barrier();                                                    \
    asm volatile("s_waitcnt lgkmcnt(0)" ::: "memory");                               \
    __builtin_amdgcn_sched_barrier(0);                                               \
    __builtin_amdgcn_s_setprio(1);                                                   \
    MFMAS                                                                            \
    __builtin_amdgcn_s_setprio(0);                                                   \
    __builtin_amdgcn_sched_barrier(0);                                               \
    asm volatile("s_waitcnt lgkmcnt(0)" ::: "memory");                               \
    VMW                                                                              \
    __builtin_amdgcn_s_barrier();                                                    \
    __builtin_amdgcn_sched_barrier(0);                                               \
} while (0)

    // ---- prologue ----
    // q rows for this WG's 256 tokens (one thread per token)
    if (tid < 256) {
        const float* xr = x + (size_t)(rowBase + tid) * 1024;
        float p = 1.0f;
        #pragma unroll
        for (int j = 0; j < 8; ++j) { p *= cosf(xr[j]); qs[tid][j] = p; }
    }
    __syncthreads();

    // vm FIFO: W(0)^2, B0(0)^2, B1(0)^2, W(1)^2  (8 outstanding)
    STAGE_W(0, 0);
    STAGE_B(0, 0, 0);
    STAGE_B(1, 0, 0);
    STAGE_W(1, 1);
    asm volatile("s_waitcnt vmcnt(6)" ::: "memory");    // W(0) landed
    __builtin_amdgcn_s_barrier();
    __builtin_amdgcn_sched_barrier(0);
    COMPUTE_A(0, 0, 0);                                 // A(0) both halves
    COMPUTE_A(1, 0, 0);
    asm volatile("s_waitcnt lgkmcnt(0)" ::: "memory");
    asm volatile("s_waitcnt vmcnt(4)" ::: "memory");    // B0(0) landed
    __builtin_amdgcn_s_barrier();
    __builtin_amdgcn_sched_barrier(0);

    #pragma unroll 2
    for (int kt = 0; kt < NKT; ++kt) {
        const int b   = kt & 1;
        const int nb  = b ^ 1;
        const int kt1 = (kt + 1) & 63;
        const int kt2 = (kt + 2) & 63;
        // -- Phase 0: quadrant (mh0, nh0) --
        LOAD_A(0); LOAD_B(bF0, 0);
        STAGE_B(0, nb, kt1);
        PHASE_TAIL(MFMA_QUAD(bF0, 0, 0);, VM4);
        // -- Phase 1: quadrant (mh0, nh1) --
        LOAD_B(bF1, 1);
        STAGE_B(1, nb, kt1);
        STAGE_W(b, kt2);
        PHASE_TAIL(MFMA_QUAD(bF1, 0, 2);, VM6);
        // -- Phase 2: quadrant (mh1, nh1) + compute A(kt+1) half0 --
        LOAD_A(1);
        PHASE_TAIL(MFMA_QUAD(bF1, 4, 2); COMPUTE_A(0, nb, nb);, );
        // -- Phase 3: quadrant (mh1, nh0) + compute A(kt+1) half1 --
        PHASE_TAIL(MFMA_QUAD(bF0, 4, 0); COMPUTE_A(1, nb, nb);, VM4);
    }

    // ---- epilogue: C/D layout col=lane&15, row=(lane>>4)*4+j ----
    const int rq = lane >> 4;
    #pragma unroll
    for (int n = 0; n < 4; ++n) {
        const int col = colBase + wc * 64 + n * 16 + rl;
        const float bv = bias[col];
        #pragma unroll
        for (int m = 0; m < 8; ++m) {
            #pragma unroll
            for (int j = 0; j < 4; ++j) {
                const int row = rowBase + wr * 128 + m * 16 + rq * 4 + j;
                C[(size_t)row * N + col] = acc[m][n][j] + bv;
            }
        }
    }
#undef STAGE_B
#undef STAGE_W
#undef COMPUTE_A
#undef LOAD_A
#undef LOAD_B
#undef MFMA_QUAD
#undef PHASE_TAIL
#undef VM4
#undef VM6
}

extern "C" void kernel_launch(void* const* d_in, const int* in_sizes, int n_in,
                              void* d_out, int out_size, void* d_ws, size_t ws_size,
                              hipStream_t stream) {
    const float* x  = (const float*)d_in[0];
    // d_in[1] = circuit_params: provably cancels (x 0.0) in the reference
    const float* w1 = (const float*)d_in[2];
    const float* b1 = (const float*)d_in[3];
    const float* w2 = (const float*)d_in[4];
    const float* b2 = (const float*)d_in[5];
    float* out = (float*)d_out;

    constexpr int M = 16384;   // B*T tokens
    constexpr int N = 1024;    // embed dim C
    constexpr int K = 4096;    // ffn dim F

    unsigned short* w2bf = (unsigned short*)d_ws;    // N*K bf16 = 8 MB

    cvt_w2<<<(N * K) / (256 * 8), 256, 0, stream>>>(w2, w2bf);
    gemm_fused<<<(M / 256) * (N / 256), 512, 0, stream>>>(x, w1, b1, w2bf, b2, out);
}